// Round 4
// baseline (940.889 us; speedup 1.0000x reference)
//
#include <hip/hip_runtime.h>

// GCN encoder: 2x (dense transform -> symmetric-normalized neighbor aggregation)
// R3: bf16x3 split MFMA GEMMs (no fp32 MFMA on CDNA4), W pre-swizzled.
// R4: aggregation gather tables bf16 -> halved beyond-L2 gather traffic.
// R5 FAILED: cross-thread fence race in ticket scan -> OOB -> abort.
// R6/R7: race-free fusions + atomic-free bucketed CSR build.
// R8 FAILED / R9 REGRESSED: cooperative grid.sync ~77-100 us each on MI355X.
// R10/R12: 6 dispatches (dependency minimum), 170.2 us best.
// R11 REGRESSED: agg+gemm LDS fusion killed occupancy; occupancy > fusion.
// R13 NEUTRAL: persistent grids (block-issue ramp was not the cost).
// R14 REGRESSED (179.4): agg1+gemm2 LDS fusion -> occupancy 27%, gather
//     latency unhidden. Aggs are gather-LATENCY bound.
// R15 REGRESSED (185.2): readlane broadcast moved DS-pipe work onto the
//     VALU pipe; aggs are L2-miss/MSHR bound, not issue bound.
// R16 NO DATA: container failed twice (audit found no deadlock/OOB; likely
//     infra flake -- R2 also showed 44s acquire anomalies).
// R17: resubmit R16 (src-block-sorted edges + LDS-scatter aggregation;
//     one wg per dst-bucket, fp32 acc tile in LDS, ds_add per edge; all 391
//     wgs co-resident sweep src space in lockstep -> L2-hit gathers) with
//     k_g4 edge unroll 4->8 (only 2 waves/SIMD at 64KB LDS; deepen MLP).

typedef __attribute__((ext_vector_type(8))) short short8;
typedef __attribute__((ext_vector_type(4))) float float4v;

constexpr int PB = 128;    // partition blocks (histogram/scatter chunks)

static __device__ __forceinline__ ushort f2bf(float f) {
  union { float f; unsigned u; } c; c.f = f;
  unsigned u = c.u;
  return (ushort)((u + 0x7fffu + ((u >> 16) & 1u)) >> 16);  // RNE
}
static __device__ __forceinline__ float bf2f(ushort h) {
  union { unsigned u; float f; } c; c.u = ((unsigned)h) << 16;
  return c.f;
}
static __device__ __forceinline__ float bfhi(unsigned packed) {
  union { unsigned u; float f; } c; c.u = packed & 0xffff0000u;
  return c.f;
}
static __device__ __forceinline__ float bflo(unsigned packed) {
  union { unsigned u; float f; } c; c.u = packed << 16;
  return c.f;
}

struct MegaParams {
  const float* x;
  const int* src;
  const int* dst;
  const float* W1;
  const float* b1;
  const float* W2;
  const float* b2;
  int N, E, NBK, EPB, GB;
  int* cnt_mat;
  int* bases;      // [NBK+1] bucket base offsets (published by scatter kernel)
  unsigned* part;
  float* dinv;
  int* col;        // src-block-sorted packed edges (src | dst_local<<25)
  ushort* h;
  ushort* h1hi;
  ushort* h1lo;
  ushort* h2;
  ushort* w1hi;
  ushort* w1lo;
  ushort* w2hi;
  ushort* w2lo;
  float* out;
};

// W swizzle: one 16x32 B-fragment tile (64 lanes).
// Layout [ktile][ntile][lane][j]: B[k=(lane>>4)*8+j][n=lane&15]
static __device__ __forceinline__ void wswz_tile(const float* __restrict__ W,
                                                 ushort* __restrict__ whi,
                                                 ushort* __restrict__ wlo,
                                                 int M, int tile, int lane) {
  int ntiles = M >> 4;
  int kt = tile / ntiles, nt = tile % ntiles;
  int colg = nt * 16 + (lane & 15);
  int krow = kt * 32 + (lane >> 4) * 8;
  size_t o = ((size_t)tile * 64 + lane) * 8;
#pragma unroll
  for (int j = 0; j < 8; j++) {
    float v = W[(size_t)(krow + j) * M + colg];
    ushort h = f2bf(v);
    whi[o + j] = h;
    wlo[o + j] = f2bf(v - bf2f(h));
  }
}

// ---- K1: bucket histogram (bid<PB) + W swizzles (bid in [PB,PB+12)) ------
__global__ __launch_bounds__(256) void k_g1(MegaParams P) {
  __shared__ int hist[512];
  int bid = blockIdx.x, t = threadIdx.x;
  if (bid >= PB) {
    int tile = (bid - PB) * 4 + (t >> 6);
    int lane = t & 63;
    if (tile < 32) wswz_tile(P.W1, P.w1hi, P.w1lo, 128, tile, lane);
    else           wswz_tile(P.W2, P.w2hi, P.w2lo, 64, tile - 32, lane);
    return;
  }
  for (int k = t; k < P.NBK; k += 256) hist[k] = 0;
  __syncthreads();
  int start = bid * P.EPB;
  int stop = min(P.E, start + P.EPB);
  for (int e = start + t * 4; e < stop; e += 1024) {
    if (e + 4 <= stop) {
      int4 d = *(const int4*)(P.dst + e);
      atomicAdd(&hist[d.x >> 7], 1);
      atomicAdd(&hist[d.y >> 7], 1);
      atomicAdd(&hist[d.z >> 7], 1);
      atomicAdd(&hist[d.w >> 7], 1);
    } else {
      for (int j = e; j < stop; j++) atomicAdd(&hist[P.dst[j] >> 7], 1);
    }
  }
  __syncthreads();
  for (int k = t; k < P.NBK; k += 256) P.cnt_mat[k * PB + bid] = hist[k];
}

// ---- gemm1 block: C[64 rows, 128] = A @ W1, fp32 A split to bf16 hi/lo ----
static __device__ void gemm1_block(int gb, const MegaParams& P) {
  constexpr int K = 128, M = 128, NT = M / 16;
  int t = threadIdx.x;
  int lane = t & 63;
  int wv = t >> 6;
  int quad = lane >> 4, lo16 = lane & 15;
  int rowbase = gb * 64 + wv * 16;
  int arow = rowbase + lo16;
  bool arow_ok = arow < P.N;
  float4v acc[NT];
#pragma unroll
  for (int nt = 0; nt < NT; nt++) acc[nt] = (float4v){0.f, 0.f, 0.f, 0.f};
  for (int kt = 0; kt < 4; kt++) {
    short8 ahi, alo;
    float av[8];
    if (arow_ok) {
      const float* ap = P.x + (size_t)arow * K + kt * 32 + quad * 8;
      float4 a0 = *(const float4*)ap;
      float4 a1 = *(const float4*)(ap + 4);
      av[0] = a0.x; av[1] = a0.y; av[2] = a0.z; av[3] = a0.w;
      av[4] = a1.x; av[5] = a1.y; av[6] = a1.z; av[7] = a1.w;
    } else {
#pragma unroll
      for (int j = 0; j < 8; j++) av[j] = 0.f;
    }
#pragma unroll
    for (int j = 0; j < 8; j++) {
      ushort hh = f2bf(av[j]);
      ahi[j] = (short)hh;
      alo[j] = (short)f2bf(av[j] - bf2f(hh));
    }
    const ushort* ph = P.w1hi + ((size_t)(kt * NT) * 64 + lane) * 8;
    const ushort* pl = P.w1lo + ((size_t)(kt * NT) * 64 + lane) * 8;
#pragma unroll
    for (int nt = 0; nt < NT; nt++) {
      short8 bhi = *(const short8*)(ph + nt * 512);
      short8 blo = *(const short8*)(pl + nt * 512);
      acc[nt] = __builtin_amdgcn_mfma_f32_16x16x32_bf16(ahi, bhi, acc[nt], 0, 0, 0);
      acc[nt] = __builtin_amdgcn_mfma_f32_16x16x32_bf16(alo, bhi, acc[nt], 0, 0, 0);
      acc[nt] = __builtin_amdgcn_mfma_f32_16x16x32_bf16(ahi, blo, acc[nt], 0, 0, 0);
    }
  }
  // D layout (m89-verified): col = lane&15, row = quad*4 + reg
#pragma unroll
  for (int nt = 0; nt < NT; nt++) {
#pragma unroll
    for (int r = 0; r < 4; r++) {
      int row = rowbase + quad * 4 + r;
      if (row < P.N) P.h[(size_t)row * M + nt * 16 + lo16] = f2bf(acc[nt][r]);
    }
  }
}

// ---- K2: partition scatter w/ self-computed prefixes (bid<PB) || gemm1 ----
__global__ __launch_bounds__(256) void k_g2(MegaParams P) {
  __shared__ int buf[256];
  __shared__ int base[512];
  __shared__ int tot[512];
  __shared__ int cur[512];
  int bid = blockIdx.x, t = threadIdx.x;
  if (bid >= PB) {
    gemm1_block(bid - PB, P);
    return;
  }
  for (int k = t; k < P.NBK; k += 256) {
    const int* row = P.cnt_mat + (size_t)k * PB;
    int pre = 0, s = 0;
    for (int b = 0; b < PB; b++) {
      int c = row[b];
      s += c;
      if (b < bid) pre += c;
    }
    tot[k] = s;
    cur[k] = pre;
  }
  __syncthreads();
  {
    int carry = 0;
    for (int b0 = 0; b0 < 512; b0 += 256) {
      int idx = b0 + t;
      int v = (idx < P.NBK) ? tot[idx] : 0;
      buf[t] = v;
      __syncthreads();
      for (int off = 1; off < 256; off <<= 1) {
        int add = (t >= off) ? buf[t - off] : 0;
        __syncthreads();
        buf[t] += add;
        __syncthreads();
      }
      base[idx] = carry + buf[t] - v;
      carry += buf[255];
      __syncthreads();
    }
  }
  for (int k = t; k < P.NBK; k += 256) cur[k] += base[k];
  if (bid == 0)
    for (int k = t; k <= P.NBK; k += 256) P.bases[k] = base[k];
  __syncthreads();
  int start = bid * P.EPB, stop = min(P.E, start + P.EPB);
  for (int e = start + t * 4; e < stop; e += 1024) {
    if (e + 4 <= stop) {
      int4 s = *(const int4*)(P.src + e);
      int4 d = *(const int4*)(P.dst + e);
      int p;
      p = atomicAdd(&cur[d.x >> 7], 1); P.part[p] = (unsigned)s.x | ((unsigned)(d.x & 127) << 25);
      p = atomicAdd(&cur[d.y >> 7], 1); P.part[p] = (unsigned)s.y | ((unsigned)(d.y & 127) << 25);
      p = atomicAdd(&cur[d.z >> 7], 1); P.part[p] = (unsigned)s.z | ((unsigned)(d.z & 127) << 25);
      p = atomicAdd(&cur[d.w >> 7], 1); P.part[p] = (unsigned)s.w | ((unsigned)(d.w & 127) << 25);
    } else {
      for (int j = e; j < stop; j++) {
        int p2 = atomicAdd(&cur[P.dst[j] >> 7], 1);
        P.part[p2] = (unsigned)P.src[j] | ((unsigned)(P.dst[j] & 127) << 25);
      }
    }
  }
}

// ---- K3: per-bucket src-block sort (LDS count/scan/place) + dinv ---------
// Output col[]: bucket's edges sorted by src>>7 (packed src | dst_local<<25).
__global__ __launch_bounds__(256) void k_g3(MegaParams P) {
  __shared__ int buf[256];
  __shared__ int cnt_d[128];
  __shared__ int cnt_s[512];
  __shared__ int cur_s[512];
  int bid = blockIdx.x, t = threadIdx.x;
  int beg = P.bases[bid], end = P.bases[bid + 1];
  if (t < 128) cnt_d[t] = 0;
  for (int k = t; k < 512; k += 256) cnt_s[k] = 0;
  __syncthreads();
  for (int e = beg + t; e < end; e += 256) {
    unsigned p = P.part[e];
    atomicAdd(&cnt_d[p >> 25], 1);
    atomicAdd(&cnt_s[(p & 0x01FFFFFFu) >> 7], 1);
  }
  __syncthreads();
  if (t < 128) {
    int node = bid * 128 + t;
    if (node < P.N) P.dinv[node] = rsqrtf((float)(cnt_d[t] + 1));  // +1 self
  }
  // exclusive scan of cnt_s[0..511] -> cur_s = beg + prefix
  int carry = 0;
  for (int b0 = 0; b0 < 512; b0 += 256) {
    int v = cnt_s[b0 + t];
    buf[t] = v;
    __syncthreads();
    for (int off = 1; off < 256; off <<= 1) {
      int add = (t >= off) ? buf[t - off] : 0;
      __syncthreads();
      buf[t] += add;
      __syncthreads();
    }
    cur_s[b0 + t] = beg + carry + buf[t] - v;
    carry += buf[255];
    __syncthreads();
  }
  for (int e = beg + t; e < end; e += 256) {
    unsigned p = P.part[e];
    int pos = atomicAdd(&cur_s[(p & 0x01FFFFFFu) >> 7], 1);
    P.col[pos] = (int)p;
  }
}

// ---- K4: agg1 via LDS scatter. One wg per dst-bucket (128 nodes). --------
// acc[128][128] fp32 = 64 KB LDS. Edges src-sorted -> lockstep L2 sweep.
// 8 gathers in flight per wave (only 2 waves/SIMD at 64KB LDS).
__global__ __launch_bounds__(256) void k_g4(MegaParams P) {
  __shared__ float acc[128 * 128];
  int b = blockIdx.x, t = threadIdx.x;
  int lane = t & 63, wv = t >> 6;
  for (int k = t; k < 128 * 128; k += 256) acc[k] = 0.f;
  int beg = P.bases[b], end = P.bases[b + 1];
  __syncthreads();
  int tot = end - beg;
  int chunk = (tot + 3) >> 2;           // contiguous per wave: keeps src order
  int cbeg = beg + wv * chunk;
  int cend = min(end, cbeg + chunk);
  for (int i = cbeg; i < cend; i += 8) {
    float w[8]; unsigned u[8]; int dl[8];
#pragma unroll
    for (int q = 0; q < 8; q++) {
      bool ok = (i + q) < cend;
      unsigned p = ok ? (unsigned)P.col[i + q] : 0u;
      int src = (int)(p & 0x01FFFFFFu);
      dl[q] = (int)(p >> 25);
      w[q] = ok ? P.dinv[src] : 0.f;
      u[q] = *(const unsigned*)(P.h + (size_t)src * 128 + lane * 2);
    }
#pragma unroll
    for (int q = 0; q < 8; q++) {
      float* ap = &acc[dl[q] * 128 + lane * 2];
      atomicAdd(ap, w[q] * bflo(u[q]));
      atomicAdd(ap + 1, w[q] * bfhi(u[q]));
    }
  }
  __syncthreads();
  // epilogue: 32 rows per wave; self-loop + dv scale + bias + relu + split
  for (int r = wv * 32; r < wv * 32 + 32; r++) {
    int node = b * 128 + r;
    if (node >= P.N) break;
    float dv = P.dinv[node];
    unsigned su = *(const unsigned*)(P.h + (size_t)node * 128 + lane * 2);
    float a0 = acc[r * 128 + lane * 2];
    float a1 = acc[r * 128 + lane * 2 + 1];
    float r0 = fmaf(dv, fmaf(dv, bflo(su), a0), P.b1[lane * 2]);
    float r1 = fmaf(dv, fmaf(dv, bfhi(su), a1), P.b1[lane * 2 + 1]);
    r0 = fmaxf(r0, 0.f);
    r1 = fmaxf(r1, 0.f);
    ushort h0 = f2bf(r0), h1 = f2bf(r1);
    ushort l0 = f2bf(r0 - bf2f(h0)), l1 = f2bf(r1 - bf2f(h1));
    ((unsigned*)P.h1hi)[(size_t)node * 64 + lane] = (unsigned)h0 | ((unsigned)h1 << 16);
    ((unsigned*)P.h1lo)[(size_t)node * 64 + lane] = (unsigned)l0 | ((unsigned)l1 << 16);
  }
}

// ---- gemm2 body: PRESPLIT bf16 hi/lo in, bf16 out, M=64 ----
static __device__ void gemm2_block(int gb, const MegaParams& P) {
  constexpr int K = 128, M = 64, NT = M / 16;
  int t = threadIdx.x;
  int lane = t & 63;
  int wv = t >> 6;
  int quad = lane >> 4, lo16 = lane & 15;
  int rowbase = gb * 64 + wv * 16;
  int arow = rowbase + lo16;
  bool arow_ok = arow < P.N;
  float4v acc[NT];
#pragma unroll
  for (int nt = 0; nt < NT; nt++) acc[nt] = (float4v){0.f, 0.f, 0.f, 0.f};
  for (int kt = 0; kt < 4; kt++) {
    short8 ahi, alo;
    if (arow_ok) {
      size_t ao = (size_t)arow * K + kt * 32 + quad * 8;
      ahi = *(const short8*)(P.h1hi + ao);
      alo = *(const short8*)(P.h1lo + ao);
    } else {
      ahi = (short8)0; alo = (short8)0;
    }
    const ushort* ph = P.w2hi + ((size_t)(kt * NT) * 64 + lane) * 8;
    const ushort* pl = P.w2lo + ((size_t)(kt * NT) * 64 + lane) * 8;
#pragma unroll
    for (int nt = 0; nt < NT; nt++) {
      short8 bhi = *(const short8*)(ph + nt * 512);
      short8 blo = *(const short8*)(pl + nt * 512);
      acc[nt] = __builtin_amdgcn_mfma_f32_16x16x32_bf16(ahi, bhi, acc[nt], 0, 0, 0);
      acc[nt] = __builtin_amdgcn_mfma_f32_16x16x32_bf16(alo, bhi, acc[nt], 0, 0, 0);
      acc[nt] = __builtin_amdgcn_mfma_f32_16x16x32_bf16(ahi, blo, acc[nt], 0, 0, 0);
    }
  }
#pragma unroll
  for (int nt = 0; nt < NT; nt++) {
#pragma unroll
    for (int r = 0; r < 4; r++) {
      int row = rowbase + quad * 4 + r;
      if (row < P.N) P.h2[(size_t)row * M + nt * 16 + lo16] = f2bf(acc[nt][r]);
    }
  }
}

__global__ __launch_bounds__(256) void k_g5(MegaParams P) {
  for (int gb = blockIdx.x; gb < P.GB; gb += gridDim.x) gemm2_block(gb, P);
}

// ---- K6: agg2 via LDS scatter, C=64, half-wave per edge. -----------------
// acc[128][64] fp32 = 32 KB LDS.
__global__ __launch_bounds__(256) void k_g6(MegaParams P) {
  __shared__ float acc[128 * 64];
  int b = blockIdx.x, t = threadIdx.x;
  int lane = t & 63, wv = t >> 6;
  int l31 = lane & 31, half = lane >> 5;
  for (int k = t; k < 128 * 64; k += 256) acc[k] = 0.f;
  int beg = P.bases[b], end = P.bases[b + 1];
  __syncthreads();
  int tot = end - beg;
  int chunk = (tot + 3) >> 2;
  int cbeg = beg + wv * chunk;
  int cend = min(end, cbeg + chunk);
  for (int i = cbeg; i < cend; i += 8) {   // 4 slots x 2 edges (half-wave)
    float w[4]; unsigned u[4]; int dl[4];
#pragma unroll
    for (int q = 0; q < 4; q++) {
      int idx = i + 2 * q + half;
      bool ok = idx < cend;
      unsigned p = ok ? (unsigned)P.col[idx] : 0u;
      int src = (int)(p & 0x01FFFFFFu);
      dl[q] = (int)(p >> 25);
      w[q] = ok ? P.dinv[src] : 0.f;
      u[q] = *(const unsigned*)(P.h2 + (size_t)src * 64 + l31 * 2);
    }
#pragma unroll
    for (int q = 0; q < 4; q++) {
      float* ap = &acc[dl[q] * 64 + l31 * 2];
      atomicAdd(ap, w[q] * bflo(u[q]));
      atomicAdd(ap + 1, w[q] * bfhi(u[q]));
    }
  }
  __syncthreads();
  for (int r = wv * 32; r < wv * 32 + 32; r++) {
    int node = b * 128 + r;
    if (node >= P.N) break;
    float dv = P.dinv[node];
    float a = acc[r * 64 + lane];
    float self = bf2f(P.h2[(size_t)node * 64 + lane]);
    P.out[(size_t)node * 64 + lane] = fmaf(dv, fmaf(dv, self, a), P.b2[lane]);
  }
}

extern "C" void kernel_launch(void* const* d_in, const int* in_sizes, int n_in,
                              void* d_out, int out_size, void* d_ws, size_t ws_size,
                              hipStream_t stream) {
  MegaParams P;
  P.x  = (const float*)d_in[0];
  const int* ei = (const int*)d_in[1];
  P.W1 = (const float*)d_in[2];
  P.b1 = (const float*)d_in[3];
  P.W2 = (const float*)d_in[4];
  P.b2 = (const float*)d_in[5];
  P.N = in_sizes[0] / 128;
  P.E = in_sizes[1] / 2;
  P.src = ei;
  P.dst = ei + P.E;
  P.NBK = (P.N + 127) / 128;                   // 391; must be <= 511
  P.EPB = ((P.E + PB - 1) / PB + 3) & ~3;      // edges per partition block, x4
  P.GB = (P.N + 63) / 64;                      // 782

  auto al = [](size_t v) { return (v + 255) & ~(size_t)255; };
  char* w = (char*)d_ws;
  P.cnt_mat = (int*)w;      w += al((size_t)P.NBK * PB * 4);
  P.bases   = (int*)w;      w += al((size_t)(P.NBK + 1) * 4);
  P.part    = (unsigned*)w; w += al((size_t)P.E * 4);
  P.dinv    = (float*)w;    w += al((size_t)P.N * 4);
  P.col     = (int*)w;      w += al((size_t)P.E * 4);
  P.h       = (ushort*)w;   w += al((size_t)P.N * 128 * 2);
  P.h1hi    = (ushort*)w;   w += al((size_t)P.N * 128 * 2);
  P.h1lo    = (ushort*)w;   w += al((size_t)P.N * 128 * 2);
  P.h2      = (ushort*)w;   w += al((size_t)P.N * 64 * 2);
  P.w1hi    = (ushort*)w;   w += al((size_t)128 * 128 * 2);
  P.w1lo    = (ushort*)w;   w += al((size_t)128 * 128 * 2);
  P.w2hi    = (ushort*)w;   w += al((size_t)128 * 64 * 2);
  P.w2lo    = (ushort*)w;   w += al((size_t)128 * 64 * 2);
  P.out = (float*)d_out;

  k_g1<<<PB + 12, 256, 0, stream>>>(P);
  k_g2<<<PB + P.GB, 256, 0, stream>>>(P);
  k_g3<<<P.NBK, 256, 0, stream>>>(P);
  k_g4<<<P.NBK, 256, 0, stream>>>(P);   // agg1: LDS scatter, src-sorted
  k_g5<<<1024, 256, 0, stream>>>(P);    // gemm2
  k_g6<<<P.NBK, 256, 0, stream>>>(P);   // agg2: LDS scatter, src-sorted
}

// Round 6
// 939.682 us; speedup vs baseline: 1.0013x; 1.0013x over previous
//
#include <hip/hip_runtime.h>

// GCN encoder: 2x (dense transform -> symmetric-normalized neighbor aggregation)
// R3: bf16x3 split MFMA GEMMs (no fp32 MFMA on CDNA4), W pre-swizzled.
// R4: aggregation gather tables bf16 -> halved beyond-L2 gather traffic.
// R5 FAILED: cross-thread fence race in ticket scan -> OOB -> abort.
// R6/R7: race-free fusions + atomic-free bucketed CSR build.
// R8 FAILED / R9 REGRESSED: cooperative grid.sync ~77-100 us each on MI355X.
// R10/R12: 6 dispatches (dependency minimum), 170.2 us best.
// R11 REGRESSED: agg+gemm LDS fusion killed occupancy; occupancy > fusion.
// R13 NEUTRAL: persistent grids (block-issue ramp was not the cost).
// R14 REGRESSED (179.4): agg1+gemm2 LDS fusion -> occupancy 27%, gather
//     latency unhidden. Aggs are gather-LATENCY bound.
// R15 REGRESSED (185.2): readlane broadcast moved DS-pipe work onto the
//     VALU pipe; aggs are L2-miss/MSHR bound, not issue bound.
// R16 NO DATA: container failed twice.
// R17 REGRESSED (941; k_g4 547us): locality WORKED (FETCH 57MB, lockstep
//     src-sweep L2-resident) but atomicAdd(float*) on the LDS tile lowered
//     to a CAS loop. NOT an occupancy problem.
// R18 FAILED (absmax 4.5e-2): ds_add_f32 via inline asm races -- the
//     compiler's waitcnt pass can't see asm DS ops, so __syncthreads()
//     emitted no lgkmcnt(0) drain; adds still in flight crossed the barrier.
// R19: R18 + explicit `s_waitcnt lgkmcnt(0)` after each edge loop (before
//     the final barrier) in k_g4/k_g6. Per-wave drain + barrier => all
//     ds_adds visible before any epilogue read.

typedef __attribute__((ext_vector_type(8))) short short8;
typedef __attribute__((ext_vector_type(4))) float float4v;

constexpr int PB = 128;    // partition blocks (histogram/scatter chunks)

static __device__ __forceinline__ ushort f2bf(float f) {
  union { float f; unsigned u; } c; c.f = f;
  unsigned u = c.u;
  return (ushort)((u + 0x7fffu + ((u >> 16) & 1u)) >> 16);  // RNE
}
static __device__ __forceinline__ float bf2f(ushort h) {
  union { unsigned u; float f; } c; c.u = ((unsigned)h) << 16;
  return c.f;
}
static __device__ __forceinline__ float bfhi(unsigned packed) {
  union { unsigned u; float f; } c; c.u = packed & 0xffff0000u;
  return c.f;
}
static __device__ __forceinline__ float bflo(unsigned packed) {
  union { unsigned u; float f; } c; c.u = packed << 16;
  return c.f;
}
// Hardware LDS fp32 atomic add (no return). byte_off is the LDS byte
// offset; each caller kernel has exactly ONE __shared__ array, so the
// array base is LDS offset 0 and byte_off = index*4.
// NOTE: increments lgkmcnt invisibly to the compiler -- caller MUST drain
// with an explicit `s_waitcnt lgkmcnt(0)` before any barrier/read.
static __device__ __forceinline__ void ds_fadd(unsigned byte_off, float v) {
  asm volatile("ds_add_f32 %0, %1" :: "v"(byte_off), "v"(v) : "memory");
}
static __device__ __forceinline__ void lgkm_drain() {
  asm volatile("s_waitcnt lgkmcnt(0)" ::: "memory");
}

struct MegaParams {
  const float* x;
  const int* src;
  const int* dst;
  const float* W1;
  const float* b1;
  const float* W2;
  const float* b2;
  int N, E, NBK, EPB, GB;
  int* cnt_mat;
  int* bases;      // [NBK+1] bucket base offsets (published by scatter kernel)
  unsigned* part;
  float* dinv;
  int* col;        // src-block-sorted packed edges (src | dst_local<<25)
  ushort* h;
  ushort* h1hi;
  ushort* h1lo;
  ushort* h2;
  ushort* w1hi;
  ushort* w1lo;
  ushort* w2hi;
  ushort* w2lo;
  float* out;
};

// W swizzle: one 16x32 B-fragment tile (64 lanes).
// Layout [ktile][ntile][lane][j]: B[k=(lane>>4)*8+j][n=lane&15]
static __device__ __forceinline__ void wswz_tile(const float* __restrict__ W,
                                                 ushort* __restrict__ whi,
                                                 ushort* __restrict__ wlo,
                                                 int M, int tile, int lane) {
  int ntiles = M >> 4;
  int kt = tile / ntiles, nt = tile % ntiles;
  int colg = nt * 16 + (lane & 15);
  int krow = kt * 32 + (lane >> 4) * 8;
  size_t o = ((size_t)tile * 64 + lane) * 8;
#pragma unroll
  for (int j = 0; j < 8; j++) {
    float v = W[(size_t)(krow + j) * M + colg];
    ushort h = f2bf(v);
    whi[o + j] = h;
    wlo[o + j] = f2bf(v - bf2f(h));
  }
}

// ---- K1: bucket histogram (bid<PB) + W swizzles (bid in [PB,PB+12)) ------
__global__ __launch_bounds__(256) void k_g1(MegaParams P) {
  __shared__ int hist[512];
  int bid = blockIdx.x, t = threadIdx.x;
  if (bid >= PB) {
    int tile = (bid - PB) * 4 + (t >> 6);
    int lane = t & 63;
    if (tile < 32) wswz_tile(P.W1, P.w1hi, P.w1lo, 128, tile, lane);
    else           wswz_tile(P.W2, P.w2hi, P.w2lo, 64, tile - 32, lane);
    return;
  }
  for (int k = t; k < P.NBK; k += 256) hist[k] = 0;
  __syncthreads();
  int start = bid * P.EPB;
  int stop = min(P.E, start + P.EPB);
  for (int e = start + t * 4; e < stop; e += 1024) {
    if (e + 4 <= stop) {
      int4 d = *(const int4*)(P.dst + e);
      atomicAdd(&hist[d.x >> 7], 1);
      atomicAdd(&hist[d.y >> 7], 1);
      atomicAdd(&hist[d.z >> 7], 1);
      atomicAdd(&hist[d.w >> 7], 1);
    } else {
      for (int j = e; j < stop; j++) atomicAdd(&hist[P.dst[j] >> 7], 1);
    }
  }
  __syncthreads();
  for (int k = t; k < P.NBK; k += 256) P.cnt_mat[k * PB + bid] = hist[k];
}

// ---- gemm1 block: C[64 rows, 128] = A @ W1, fp32 A split to bf16 hi/lo ----
static __device__ void gemm1_block(int gb, const MegaParams& P) {
  constexpr int K = 128, M = 128, NT = M / 16;
  int t = threadIdx.x;
  int lane = t & 63;
  int wv = t >> 6;
  int quad = lane >> 4, lo16 = lane & 15;
  int rowbase = gb * 64 + wv * 16;
  int arow = rowbase + lo16;
  bool arow_ok = arow < P.N;
  float4v acc[NT];
#pragma unroll
  for (int nt = 0; nt < NT; nt++) acc[nt] = (float4v){0.f, 0.f, 0.f, 0.f};
  for (int kt = 0; kt < 4; kt++) {
    short8 ahi, alo;
    float av[8];
    if (arow_ok) {
      const float* ap = P.x + (size_t)arow * K + kt * 32 + quad * 8;
      float4 a0 = *(const float4*)ap;
      float4 a1 = *(const float4*)(ap + 4);
      av[0] = a0.x; av[1] = a0.y; av[2] = a0.z; av[3] = a0.w;
      av[4] = a1.x; av[5] = a1.y; av[6] = a1.z; av[7] = a1.w;
    } else {
#pragma unroll
      for (int j = 0; j < 8; j++) av[j] = 0.f;
    }
#pragma unroll
    for (int j = 0; j < 8; j++) {
      ushort hh = f2bf(av[j]);
      ahi[j] = (short)hh;
      alo[j] = (short)f2bf(av[j] - bf2f(hh));
    }
    const ushort* ph = P.w1hi + ((size_t)(kt * NT) * 64 + lane) * 8;
    const ushort* pl = P.w1lo + ((size_t)(kt * NT) * 64 + lane) * 8;
#pragma unroll
    for (int nt = 0; nt < NT; nt++) {
      short8 bhi = *(const short8*)(ph + nt * 512);
      short8 blo = *(const short8*)(pl + nt * 512);
      acc[nt] = __builtin_amdgcn_mfma_f32_16x16x32_bf16(ahi, bhi, acc[nt], 0, 0, 0);
      acc[nt] = __builtin_amdgcn_mfma_f32_16x16x32_bf16(alo, bhi, acc[nt], 0, 0, 0);
      acc[nt] = __builtin_amdgcn_mfma_f32_16x16x32_bf16(ahi, blo, acc[nt], 0, 0, 0);
    }
  }
  // D layout (m89-verified): col = lane&15, row = quad*4 + reg
#pragma unroll
  for (int nt = 0; nt < NT; nt++) {
#pragma unroll
    for (int r = 0; r < 4; r++) {
      int row = rowbase + quad * 4 + r;
      if (row < P.N) P.h[(size_t)row * M + nt * 16 + lo16] = f2bf(acc[nt][r]);
    }
  }
}

// ---- K2: partition scatter w/ self-computed prefixes (bid<PB) || gemm1 ----
__global__ __launch_bounds__(256) void k_g2(MegaParams P) {
  __shared__ int buf[256];
  __shared__ int base[512];
  __shared__ int tot[512];
  __shared__ int cur[512];
  int bid = blockIdx.x, t = threadIdx.x;
  if (bid >= PB) {
    gemm1_block(bid - PB, P);
    return;
  }
  for (int k = t; k < P.NBK; k += 256) {
    const int* row = P.cnt_mat + (size_t)k * PB;
    int pre = 0, s = 0;
    for (int b = 0; b < PB; b++) {
      int c = row[b];
      s += c;
      if (b < bid) pre += c;
    }
    tot[k] = s;
    cur[k] = pre;
  }
  __syncthreads();
  {
    int carry = 0;
    for (int b0 = 0; b0 < 512; b0 += 256) {
      int idx = b0 + t;
      int v = (idx < P.NBK) ? tot[idx] : 0;
      buf[t] = v;
      __syncthreads();
      for (int off = 1; off < 256; off <<= 1) {
        int add = (t >= off) ? buf[t - off] : 0;
        __syncthreads();
        buf[t] += add;
        __syncthreads();
      }
      base[idx] = carry + buf[t] - v;
      carry += buf[255];
      __syncthreads();
    }
  }
  for (int k = t; k < P.NBK; k += 256) cur[k] += base[k];
  if (bid == 0)
    for (int k = t; k <= P.NBK; k += 256) P.bases[k] = base[k];
  __syncthreads();
  int start = bid * P.EPB, stop = min(P.E, start + P.EPB);
  for (int e = start + t * 4; e < stop; e += 1024) {
    if (e + 4 <= stop) {
      int4 s = *(const int4*)(P.src + e);
      int4 d = *(const int4*)(P.dst + e);
      int p;
      p = atomicAdd(&cur[d.x >> 7], 1); P.part[p] = (unsigned)s.x | ((unsigned)(d.x & 127) << 25);
      p = atomicAdd(&cur[d.y >> 7], 1); P.part[p] = (unsigned)s.y | ((unsigned)(d.y & 127) << 25);
      p = atomicAdd(&cur[d.z >> 7], 1); P.part[p] = (unsigned)s.z | ((unsigned)(d.z & 127) << 25);
      p = atomicAdd(&cur[d.w >> 7], 1); P.part[p] = (unsigned)s.w | ((unsigned)(d.w & 127) << 25);
    } else {
      for (int j = e; j < stop; j++) {
        int p2 = atomicAdd(&cur[P.dst[j] >> 7], 1);
        P.part[p2] = (unsigned)P.src[j] | ((unsigned)(P.dst[j] & 127) << 25);
      }
    }
  }
}

// ---- K3: per-bucket src-block sort (LDS count/scan/place) + dinv ---------
// Output col[]: bucket's edges sorted by src>>7 (packed src | dst_local<<25).
__global__ __launch_bounds__(256) void k_g3(MegaParams P) {
  __shared__ int buf[256];
  __shared__ int cnt_d[128];
  __shared__ int cnt_s[512];
  __shared__ int cur_s[512];
  int bid = blockIdx.x, t = threadIdx.x;
  int beg = P.bases[bid], end = P.bases[bid + 1];
  if (t < 128) cnt_d[t] = 0;
  for (int k = t; k < 512; k += 256) cnt_s[k] = 0;
  __syncthreads();
  for (int e = beg + t; e < end; e += 256) {
    unsigned p = P.part[e];
    atomicAdd(&cnt_d[p >> 25], 1);
    atomicAdd(&cnt_s[(p & 0x01FFFFFFu) >> 7], 1);
  }
  __syncthreads();
  if (t < 128) {
    int node = bid * 128 + t;
    if (node < P.N) P.dinv[node] = rsqrtf((float)(cnt_d[t] + 1));  // +1 self
  }
  // exclusive scan of cnt_s[0..511] -> cur_s = beg + prefix
  int carry = 0;
  for (int b0 = 0; b0 < 512; b0 += 256) {
    int v = cnt_s[b0 + t];
    buf[t] = v;
    __syncthreads();
    for (int off = 1; off < 256; off <<= 1) {
      int add = (t >= off) ? buf[t - off] : 0;
      __syncthreads();
      buf[t] += add;
      __syncthreads();
    }
    cur_s[b0 + t] = beg + carry + buf[t] - v;
    carry += buf[255];
    __syncthreads();
  }
  for (int e = beg + t; e < end; e += 256) {
    unsigned p = P.part[e];
    int pos = atomicAdd(&cur_s[(p & 0x01FFFFFFu) >> 7], 1);
    P.col[pos] = (int)p;
  }
}

// ---- K4: agg1 via LDS scatter. One wg per dst-bucket (128 nodes). --------
// acc[128][128] fp32 = 64 KB LDS. Edges src-sorted -> lockstep L2 sweep.
// ds_add_f32 per channel pair (hardware LDS fp add, fire-and-forget).
__global__ __launch_bounds__(256) void k_g4(MegaParams P) {
  __shared__ float acc[128 * 128];
  int b = blockIdx.x, t = threadIdx.x;
  int lane = t & 63, wv = t >> 6;
  for (int k = t; k < 128 * 128; k += 256) acc[k] = 0.f;
  int beg = P.bases[b], end = P.bases[b + 1];
  __syncthreads();
  int tot = end - beg;
  int chunk = (tot + 3) >> 2;           // contiguous per wave: keeps src order
  int cbeg = beg + wv * chunk;
  int cend = min(end, cbeg + chunk);
  for (int i = cbeg; i < cend; i += 8) {
    float w[8]; unsigned u[8]; int dl[8];
#pragma unroll
    for (int q = 0; q < 8; q++) {
      bool ok = (i + q) < cend;
      unsigned p = ok ? (unsigned)P.col[i + q] : 0u;
      int src = (int)(p & 0x01FFFFFFu);
      dl[q] = (int)(p >> 25);
      w[q] = ok ? P.dinv[src] : 0.f;
      u[q] = *(const unsigned*)(P.h + (size_t)src * 128 + lane * 2);
    }
#pragma unroll
    for (int q = 0; q < 8; q++) {
      unsigned off = (unsigned)((dl[q] * 128 + lane * 2) * 4);
      ds_fadd(off,     w[q] * bflo(u[q]));
      ds_fadd(off + 4, w[q] * bfhi(u[q]));
    }
  }
  lgkm_drain();     // asm ds_adds are invisible to the waitcnt pass (R18 bug)
  __syncthreads();  // all waves drained -> all adds visible
  // epilogue: 32 rows per wave; self-loop + dv scale + bias + relu + split
  for (int r = wv * 32; r < wv * 32 + 32; r++) {
    int node = b * 128 + r;
    if (node >= P.N) break;
    float dv = P.dinv[node];
    unsigned su = *(const unsigned*)(P.h + (size_t)node * 128 + lane * 2);
    float a0 = acc[r * 128 + lane * 2];
    float a1 = acc[r * 128 + lane * 2 + 1];
    float r0 = fmaf(dv, fmaf(dv, bflo(su), a0), P.b1[lane * 2]);
    float r1 = fmaf(dv, fmaf(dv, bfhi(su), a1), P.b1[lane * 2 + 1]);
    r0 = fmaxf(r0, 0.f);
    r1 = fmaxf(r1, 0.f);
    ushort h0 = f2bf(r0), h1 = f2bf(r1);
    ushort l0 = f2bf(r0 - bf2f(h0)), l1 = f2bf(r1 - bf2f(h1));
    ((unsigned*)P.h1hi)[(size_t)node * 64 + lane] = (unsigned)h0 | ((unsigned)h1 << 16);
    ((unsigned*)P.h1lo)[(size_t)node * 64 + lane] = (unsigned)l0 | ((unsigned)l1 << 16);
  }
}

// ---- gemm2 body: PRESPLIT bf16 hi/lo in, bf16 out, M=64 ----
static __device__ void gemm2_block(int gb, const MegaParams& P) {
  constexpr int K = 128, M = 64, NT = M / 16;
  int t = threadIdx.x;
  int lane = t & 63;
  int wv = t >> 6;
  int quad = lane >> 4, lo16 = lane & 15;
  int rowbase = gb * 64 + wv * 16;
  int arow = rowbase + lo16;
  bool arow_ok = arow < P.N;
  float4v acc[NT];
#pragma unroll
  for (int nt = 0; nt < NT; nt++) acc[nt] = (float4v){0.f, 0.f, 0.f, 0.f};
  for (int kt = 0; kt < 4; kt++) {
    short8 ahi, alo;
    if (arow_ok) {
      size_t ao = (size_t)arow * K + kt * 32 + quad * 8;
      ahi = *(const short8*)(P.h1hi + ao);
      alo = *(const short8*)(P.h1lo + ao);
    } else {
      ahi = (short8)0; alo = (short8)0;
    }
    const ushort* ph = P.w2hi + ((size_t)(kt * NT) * 64 + lane) * 8;
    const ushort* pl = P.w2lo + ((size_t)(kt * NT) * 64 + lane) * 8;
#pragma unroll
    for (int nt = 0; nt < NT; nt++) {
      short8 bhi = *(const short8*)(ph + nt * 512);
      short8 blo = *(const short8*)(pl + nt * 512);
      acc[nt] = __builtin_amdgcn_mfma_f32_16x16x32_bf16(ahi, bhi, acc[nt], 0, 0, 0);
      acc[nt] = __builtin_amdgcn_mfma_f32_16x16x32_bf16(alo, bhi, acc[nt], 0, 0, 0);
      acc[nt] = __builtin_amdgcn_mfma_f32_16x16x32_bf16(ahi, blo, acc[nt], 0, 0, 0);
    }
  }
#pragma unroll
  for (int nt = 0; nt < NT; nt++) {
#pragma unroll
    for (int r = 0; r < 4; r++) {
      int row = rowbase + quad * 4 + r;
      if (row < P.N) P.h2[(size_t)row * M + nt * 16 + lo16] = f2bf(acc[nt][r]);
    }
  }
}

__global__ __launch_bounds__(256) void k_g5(MegaParams P) {
  for (int gb = blockIdx.x; gb < P.GB; gb += gridDim.x) gemm2_block(gb, P);
}

// ---- K6: agg2 via LDS scatter, C=64, half-wave per edge. -----------------
// acc[128][64] fp32 = 32 KB LDS.
__global__ __launch_bounds__(256) void k_g6(MegaParams P) {
  __shared__ float acc[128 * 64];
  int b = blockIdx.x, t = threadIdx.x;
  int lane = t & 63, wv = t >> 6;
  int l31 = lane & 31, half = lane >> 5;
  for (int k = t; k < 128 * 64; k += 256) acc[k] = 0.f;
  int beg = P.bases[b], end = P.bases[b + 1];
  __syncthreads();
  int tot = end - beg;
  int chunk = (tot + 3) >> 2;
  int cbeg = beg + wv * chunk;
  int cend = min(end, cbeg + chunk);
  for (int i = cbeg; i < cend; i += 8) {   // 4 slots x 2 edges (half-wave)
    float w[4]; unsigned u[4]; int dl[4];
#pragma unroll
    for (int q = 0; q < 4; q++) {
      int idx = i + 2 * q + half;
      bool ok = idx < cend;
      unsigned p = ok ? (unsigned)P.col[idx] : 0u;
      int src = (int)(p & 0x01FFFFFFu);
      dl[q] = (int)(p >> 25);
      w[q] = ok ? P.dinv[src] : 0.f;
      u[q] = *(const unsigned*)(P.h2 + (size_t)src * 64 + l31 * 2);
    }
#pragma unroll
    for (int q = 0; q < 4; q++) {
      unsigned off = (unsigned)((dl[q] * 64 + l31 * 2) * 4);
      ds_fadd(off,     w[q] * bflo(u[q]));
      ds_fadd(off + 4, w[q] * bfhi(u[q]));
    }
  }
  lgkm_drain();     // asm ds_adds are invisible to the waitcnt pass (R18 bug)
  __syncthreads();  // all waves drained -> all adds visible
  for (int r = wv * 32; r < wv * 32 + 32; r++) {
    int node = b * 128 + r;
    if (node >= P.N) break;
    float dv = P.dinv[node];
    float a = acc[r * 64 + lane];
    float self = bf2f(P.h2[(size_t)node * 64 + lane]);
    P.out[(size_t)node * 64 + lane] = fmaf(dv, fmaf(dv, self, a), P.b2[lane]);
  }
}

extern "C" void kernel_launch(void* const* d_in, const int* in_sizes, int n_in,
                              void* d_out, int out_size, void* d_ws, size_t ws_size,
                              hipStream_t stream) {
  MegaParams P;
  P.x  = (const float*)d_in[0];
  const int* ei = (const int*)d_in[1];
  P.W1 = (const float*)d_in[2];
  P.b1 = (const float*)d_in[3];
  P.W2 = (const float*)d_in[4];
  P.b2 = (const float*)d_in[5];
  P.N = in_sizes[0] / 128;
  P.E = in_sizes[1] / 2;
  P.src = ei;
  P.dst = ei + P.E;
  P.NBK = (P.N + 127) / 128;                   // 391; must be <= 511
  P.EPB = ((P.E + PB - 1) / PB + 3) & ~3;      // edges per partition block, x4
  P.GB = (P.N + 63) / 64;                      // 782

  auto al = [](size_t v) { return (v + 255) & ~(size_t)255; };
  char* w = (char*)d_ws;
  P.cnt_mat = (int*)w;      w += al((size_t)P.NBK * PB * 4);
  P.bases   = (int*)w;      w += al((size_t)(P.NBK + 1) * 4);
  P.part    = (unsigned*)w; w += al((size_t)P.E * 4);
  P.dinv    = (float*)w;    w += al((size_t)P.N * 4);
  P.col     = (int*)w;      w += al((size_t)P.E * 4);
  P.h       = (ushort*)w;   w += al((size_t)P.N * 128 * 2);
  P.h1hi    = (ushort*)w;   w += al((size_t)P.N * 128 * 2);
  P.h1lo    = (ushort*)w;   w += al((size_t)P.N * 128 * 2);
  P.h2      = (ushort*)w;   w += al((size_t)P.N * 64 * 2);
  P.w1hi    = (ushort*)w;   w += al((size_t)128 * 128 * 2);
  P.w1lo    = (ushort*)w;   w += al((size_t)128 * 128 * 2);
  P.w2hi    = (ushort*)w;   w += al((size_t)128 * 64 * 2);
  P.w2lo    = (ushort*)w;   w += al((size_t)128 * 64 * 2);
  P.out = (float*)d_out;

  k_g1<<<PB + 12, 256, 0, stream>>>(P);
  k_g2<<<PB + P.GB, 256, 0, stream>>>(P);
  k_g3<<<P.NBK, 256, 0, stream>>>(P);
  k_g4<<<P.NBK, 256, 0, stream>>>(P);   // agg1: LDS scatter, ds_add_f32
  k_g5<<<1024, 256, 0, stream>>>(P);    // gemm2
  k_g6<<<P.NBK, 256, 0, stream>>>(P);   // agg2: LDS scatter, ds_add_f32
}